// Round 8
// baseline (312.956 us; speedup 1.0000x reference)
//
#include <hip/hip_runtime.h>

#define NEDGE 50000
#define NNODE 12000
#define NB    392
#define NT    100352  // NB*256

typedef _Float16 f16;
typedef _Float16 h8 __attribute__((ext_vector_type(8)));
typedef float f4 __attribute__((ext_vector_type(4)));
typedef float fv16 __attribute__((ext_vector_type(16)));

// workspace layout (bytes) — identical to r5 (HW-verified) + barrier counter
#define O_EDGEH 0ull            // edge f16 padded [50176][64]        = 6,422,528
#define O_W2G   6422528ull      // swizzled W2 f16 (64 chunks x 16KB) = 1,048,576
#define O_B2G   7471104ull      // swizzled b2 f16 (8KB), follows w2g (tail DMA)
#define O_W1G   7479296ull      // swizzled W1 f16 (16KB), absorbs tail overread
#define O_WG    7495680ull      // GRU combined weights f16 (64KB)
#define O_AGG   7561216ull      // agg f32 [12000][64]                = 3,072,000
#define O_CNT   10633216ull     // barrier counter (8B, memset to 0 each launch)

__device__ __forceinline__ void async16(const void* g, void* l) {
  __builtin_amdgcn_global_load_lds((const __attribute__((address_space(1))) void*)g,
                                   (__attribute__((address_space(3))) void*)l, 16, 0, 0);
}

__device__ __forceinline__ fv16 zero16() {
  fv16 z;
#pragma unroll
  for (int i = 0; i < 16; ++i) z[i] = 0.f;
  return z;
}

// manual grid barrier: all NB blocks are co-resident (grid <= resident capacity)
__device__ __forceinline__ void gbar(int* cnt, int target) {
  __syncthreads();
  if (threadIdx.x == 0) {
    __threadfence();  // release all prior writes device-wide
    __hip_atomic_fetch_add(cnt, 1, __ATOMIC_ACQ_REL, __HIP_MEMORY_SCOPE_AGENT);
    while (__hip_atomic_load(cnt, __ATOMIC_ACQUIRE, __HIP_MEMORY_SCOPE_AGENT) < target)
      __builtin_amdgcn_s_sleep(2);
  }
  __syncthreads();
}

__global__ __launch_bounds__(256, 2) void k_fused(
    const float* __restrict__ node, const float* __restrict__ edge, const float* __restrict__ hid,
    const int* __restrict__ src, const int* __restrict__ dst,
    const float* __restrict__ W1, const float* __restrict__ b1,
    const float* __restrict__ W2, const float* __restrict__ b2,
    const float* __restrict__ Wih, const float* __restrict__ Whh,
    const float* __restrict__ bih, const float* __restrict__ bhh,
    const float* __restrict__ gamma, const float* __restrict__ beta,
    f16* __restrict__ edgeh, f16* __restrict__ w1g, f16* __restrict__ w2g,
    f16* __restrict__ b2g, f16* __restrict__ wg, float* __restrict__ agg,
    int* __restrict__ cnt, float* __restrict__ out) {
  // LDS map (52736 B): phase B == r5 k_msg exactly; phase C xh_s + scalars
  __shared__ __align__(16) char lds[52736];
  int t = threadIdx.x;
  int bid = blockIdx.x;
  int tid = bid * 256 + t;

  // ================= phase A: prep (r5 k_prep, grid-strided) =================
  for (int i = tid; i < 192000; i += NT)  // agg zero
    ((f4*)agg)[i] = (f4){0.f, 0.f, 0.f, 0.f};
  for (int i = tid; i < 401408; i += NT) {  // edgeh cast, 8 elems/thread (EPAD rows, pad zeroed)
    long e = (long)i >> 3;
    int c = (i & 7) * 8;
    h8 o = {};
    if (e < NEDGE) {
      const float* p = edge + e * 64 + c;
      f4 v0 = *(const f4*)p, v1 = *(const f4*)(p + 4);
#pragma unroll
      for (int j = 0; j < 4; ++j) { o[j] = (f16)v0[j]; o[4 + j] = (f16)v1[j]; }
    }
    *(h8*)(edgeh + e * 64 + c) = o;
  }
  for (int id = tid; id < 524288; id += NT) {  // w2g swizzle (32x32x16 B-granule order)
    int i = id & 7, l = (id >> 3) & 63, nh = (id >> 9) & 1, s = (id >> 10) & 7, h = id >> 13;
    int n = nh * 32 + (l & 31), j = s * 16 + ((l >> 5) << 3) + i;
    w2g[id] = (f16)W2[(h * 64 + n) * 128 + j];
  }
  for (int id = tid; id < 4096; id += NT) {  // b2g
    int i = id & 7, l = (id >> 3) & 63, nh = (id >> 9) & 1, s = id >> 10;
    int n = nh * 32 + (l & 31), k = s * 16 + ((l >> 5) << 3) + i;
    b2g[id] = (f16)b2[k * 64 + n];
  }
  for (int id = tid; id < 8192; id += NT) {  // w1g
    int i = id & 7, l = (id >> 3) & 63, nt2 = (id >> 9) & 3, s = id >> 11;
    int n = nt2 * 32 + (l & 31), k = s * 16 + ((l >> 5) << 3) + i;
    w1g[id] = (f16)W1[n * 64 + k];
  }
  for (int id = tid; id < 32768; id += NT) {  // wg: [128k][256n], 16x16x32 granule order
    int ii = id & 7, l = (id >> 3) & 63, tt = (id >> 9) & 15, s = id >> 13;
    int k = s * 32 + ((l >> 4) << 3) + ii, n = tt * 16 + (l & 15);
    float v;
    if (n < 128) v = (k < 64) ? Wih[n * 64 + k] : Whh[n * 64 + (k - 64)];
    else if (n < 192) v = (k < 64) ? Wih[n * 64 + k] : 0.f;
    else v = (k < 64) ? 0.f : Whh[(n - 64) * 64 + (k - 64)];
    wg[id] = (f16)v;
  }
  gbar(cnt, NB);

  // ================= phase B: msg GEMM + scatter (r5 k_msg verbatim, e_base=bid*128) =================
  {
    f16* eh_s = (f16*)lds;
    char* bbuf = lds;
    f16* vT = (f16*)(lds + 32768);
    int* ssrc = (int*)(lds + 51200);
    int* sdst = (int*)(lds + 51712);
    float* b1s = (float*)(lds + 52224);
    int e_base = bid * 128;

    if (t < 128) {
      int eg = e_base + t;
      bool valid = eg < NEDGE;
      ssrc[t] = valid ? src[eg] : 0;
      sdst[t] = valid ? dst[eg] : 0;
    } else {
      b1s[t - 128] = b1[t - 128];
    }
    {
      int e = t >> 1, half = t & 1;
      int eg = e_base + e;
      int si = (eg < NEDGE) ? src[eg] : 0;
      const f4* nr = (const f4*)(node + (long)si * 64 + half * 32);
#pragma unroll
      for (int b = 0; b < 4; ++b) {
        f4 v0 = nr[b * 2], v1 = nr[b * 2 + 1];
        h8 pk;
#pragma unroll
        for (int m = 0; m < 4; ++m) { pk[m] = (f16)v0[m]; pk[4 + m] = (f16)v1[m]; }
        *(h8*)(vT + e * 72 + (half * 4 + b) * 8) = pk;
      }
    }
    __syncthreads();

    int wave = t >> 6, lane = t & 63;
    int wm = wave & 1, wn = wave >> 1;
    int l31 = lane & 31, lh = lane >> 5;

    // phase 1: eh = relu(edge @ W1^T + b1)
    {
      h8 afr[2][4];
#pragma unroll
      for (int mt = 0; mt < 2; ++mt)
#pragma unroll
        for (int s = 0; s < 4; ++s)
          afr[mt][s] = *(const h8*)(edgeh + (long)(e_base + wm * 64 + mt * 32 + l31) * 64 + s * 16 + lh * 8);
      h8 bfr[2][4];
#pragma unroll
      for (int nt2 = 0; nt2 < 2; ++nt2)
#pragma unroll
        for (int s = 0; s < 4; ++s)
          bfr[nt2][s] = *(const h8*)(w1g + ((s * 4 + wn * 2 + nt2) * 64 + lane) * 8);
      fv16 acc_eh[2][2];
#pragma unroll
      for (int mt = 0; mt < 2; ++mt)
#pragma unroll
        for (int nt2 = 0; nt2 < 2; ++nt2) acc_eh[mt][nt2] = zero16();
#pragma unroll
      for (int s = 0; s < 4; ++s)
#pragma unroll
        for (int mt = 0; mt < 2; ++mt)
#pragma unroll
          for (int nt2 = 0; nt2 < 2; ++nt2)
            acc_eh[mt][nt2] = __builtin_amdgcn_mfma_f32_32x32x16_f16(afr[mt][s], bfr[nt2][s], acc_eh[mt][nt2], 0, 0, 0);
#pragma unroll
      for (int mt = 0; mt < 2; ++mt)
#pragma unroll
        for (int nt2 = 0; nt2 < 2; ++nt2)
#pragma unroll
          for (int rr = 0; rr < 16; ++rr) {
            int row = (rr & 3) + 8 * (rr >> 2) + 4 * lh;
            int e = wm * 64 + mt * 32 + row;
            int n = wn * 64 + nt2 * 32 + l31;
            float val = fmaxf(acc_eh[mt][nt2][rr] + b1s[n], 0.f);
            int o = n >> 3;
            eh_s[e * 128 + ((o ^ (e & 15)) << 3) + (n & 7)] = (f16)val;
          }
    }
    __syncthreads();

    // phase 2: eh fragments -> registers
    h8 ehreg[2][8];
#pragma unroll
    for (int mt = 0; mt < 2; ++mt) {
      int e = wm * 64 + mt * 32 + l31;
#pragma unroll
      for (int s = 0; s < 8; ++s) {
        int o = (s * 2 + lh) ^ (e & 15);
        ehreg[mt][s] = *(const h8*)(eh_s + e * 128 + o * 8);
      }
    }
    __syncthreads();  // eh_s dead -> bbuf free

    const char* w2b = (const char*)w2g;
#pragma unroll
    for (int r = 0; r < 4; ++r) async16(w2b + r * 4096 + t * 16, bbuf + r * 4096 + t * 16);

    fv16 acc[2];
    acc[0] = zero16(); acc[1] = zero16();
    const f16* vrow0 = vT + (wm * 64 + l31) * 72;
    const f16* vrow1 = vT + (wm * 64 + 32 + l31) * 72;

#pragma unroll 1
    for (int hb = 0; hb < 8; ++hb) {
      h8 vh0 = *(const h8*)(vrow0 + hb * 8);
      h8 vh1 = *(const h8*)(vrow1 + hb * 8);
#pragma unroll
      for (int hh = 0; hh < 8; ++hh) {
        int h = hb * 8 + hh;
        __syncthreads();
        {
          const char* gsrc = w2b + (long)(h + 1) * 16384;  // h=63: b2g chunk + harmless overread
          char* ldst = bbuf + ((h + 1) & 1) * 16384;
#pragma unroll
          for (int r = 0; r < 4; ++r) async16(gsrc + r * 4096 + t * 16, ldst + r * 4096 + t * 16);
        }
        const f16* bp = (const f16*)(bbuf + (h & 1) * 16384) + (wn * 64 + lane) * 8;
        f16 v0 = vh0[hh], v1 = vh1[hh];
#pragma unroll
        for (int s = 0; s < 8; ++s) {
          h8 bf = *(const h8*)(bp + s * 1024);
          h8 a0 = ehreg[0][s] * v0;
          acc[0] = __builtin_amdgcn_mfma_f32_32x32x16_f16(a0, bf, acc[0], 0, 0, 0);
          h8 a1 = ehreg[1][s] * v1;
          acc[1] = __builtin_amdgcn_mfma_f32_32x32x16_f16(a1, bf, acc[1], 0, 0, 0);
        }
      }
    }
    __syncthreads();  // b2 tail chunk landed (in bbuf[0])
    {
      const f16* bp = (const f16*)bbuf + (wn * 64 + lane) * 8;
#pragma unroll
      for (int s = 0; s < 4; ++s) {
        h8 bf = *(const h8*)(bp + s * 1024);
        h8 a0 = *(const h8*)(vrow0 + (s * 2 + lh) * 8);
        h8 a1 = *(const h8*)(vrow1 + (s * 2 + lh) * 8);
        acc[0] = __builtin_amdgcn_mfma_f32_32x32x16_f16(a0, bf, acc[0], 0, 0, 0);
        acc[1] = __builtin_amdgcn_mfma_f32_32x32x16_f16(a1, bf, acc[1], 0, 0, 0);
      }
    }
    // epilogue: atomic scatter
    int n = wn * 32 + l31;
#pragma unroll
    for (int mt = 0; mt < 2; ++mt)
#pragma unroll
      for (int r = 0; r < 16; ++r) {
        int el = wm * 64 + mt * 32 + (r & 3) + 8 * (r >> 2) + 4 * lh;
        if (e_base + el < NEDGE)
          atomicAdd(&agg[(long)sdst[el] * 64 + n], acc[mt][r]);
      }
  }
  gbar(cnt, 2 * NB);

  // ================= phase C: GRU + LayerNorm (r5 k_node, blocks 0..93) =================
  if (bid >= 94) return;
  {
    f16* xh_s = (f16*)lds;                       // 34816 B
    float* bsum = (float*)(lds + 34816);         // 512 B
    float* bin_s = (float*)(lds + 35328);        // 256 B
    float* bhn_s = (float*)(lds + 35584);        // 256 B
    float* gam_s = (float*)(lds + 35840);        // 256 B
    float* bet_s = (float*)(lds + 36096);        // 256 B
    int n0 = bid * 128;

    if (t < 128) bsum[t] = bih[t] + bhh[t];
    else if (t < 192) bin_s[t - 128] = bih[t];
    else bhn_s[t - 192] = bhh[t - 64];
    if (t < 64) gam_s[t] = gamma[t];
    else if (t < 128) bet_s[t - 64] = beta[t - 64];

    {
      int m = t >> 1, half = t & 1;
      int mg = n0 + m;
      bool vld = mg < NNODE;
      const float* sp = half ? (hid + (long)mg * 64) : (agg + (long)mg * 64);
#pragma unroll
      for (int jj = 0; jj < 8; ++jj) {
        f4 v0 = {0, 0, 0, 0}, v1 = {0, 0, 0, 0};
        if (vld) { v0 = *(const f4*)(sp + jj * 8); v1 = *(const f4*)(sp + jj * 8 + 4); }
        h8 pk;
#pragma unroll
        for (int m2 = 0; m2 < 4; ++m2) {
          pk[m2] = (f16)(half ? v0[m2] : fmaxf(v0[m2], 0.f));
          pk[4 + m2] = (f16)(half ? v1[m2] : fmaxf(v1[m2], 0.f));
        }
        *(h8*)(xh_s + m * 136 + half * 64 + jj * 8) = pk;
      }
    }
    __syncthreads();

    int wave = t >> 6, lane = t & 63;
    int l15 = lane & 15, lq = lane >> 4;

    f4 acc[2][16];
#pragma unroll
    for (int g = 0; g < 2; ++g)
#pragma unroll
      for (int tt = 0; tt < 16; ++tt) acc[g][tt] = (f4){0.f, 0.f, 0.f, 0.f};
#pragma unroll
    for (int s = 0; s < 4; ++s) {
      h8 a0 = *(const h8*)(xh_s + (wave * 32 + l15) * 136 + s * 32 + lq * 8);
      h8 a1 = *(const h8*)(xh_s + (wave * 32 + 16 + l15) * 136 + s * 32 + lq * 8);
#pragma unroll
      for (int tt = 0; tt < 16; ++tt) {
        h8 b = *(const h8*)(wg + ((s * 16 + tt) * 64 + lane) * 8);
        acc[0][tt] = __builtin_amdgcn_mfma_f32_16x16x32_f16(a0, b, acc[0][tt], 0, 0, 0);
        acc[1][tt] = __builtin_amdgcn_mfma_f32_16x16x32_f16(a1, b, acc[1][tt], 0, 0, 0);
      }
    }
#pragma unroll
    for (int g = 0; g < 2; ++g)
#pragma unroll
      for (int r = 0; r < 4; ++r) {
        int mg = n0 + wave * 32 + g * 16 + lq * 4 + r;
        bool vld = mg < NNODE;
        float o[4], ssum = 0.f, s2 = 0.f;
#pragma unroll
        for (int t0 = 0; t0 < 4; ++t0) {
          int f = t0 * 16 + l15;
          float rpre = acc[g][t0][r] + bsum[f];
          float zpre = acc[g][4 + t0][r] + bsum[64 + f];
          float ginv = acc[g][8 + t0][r] + bin_s[f];
          float ghnv = acc[g][12 + t0][r] + bhn_s[f];
          float rr = 1.f / (1.f + __expf(-rpre));
          float zz = 1.f / (1.f + __expf(-zpre));
          float hv = vld ? hid[(long)mg * 64 + f] : 0.f;
          float nn = tanhf(ginv + rr * ghnv);
          float oo = (1.f - zz) * nn + zz * hv;
          o[t0] = oo; ssum += oo; s2 += oo * oo;
        }
#pragma unroll
        for (int d = 1; d < 16; d <<= 1) {
          ssum += __shfl_xor(ssum, d);
          s2 += __shfl_xor(s2, d);
        }
        float mu = ssum * (1.f / 64.f);
        float var = s2 * (1.f / 64.f) - mu * mu;
        float rstd = rsqrtf(var + 1e-5f);
        if (vld)
#pragma unroll
          for (int t0 = 0; t0 < 4; ++t0) {
            int f = t0 * 16 + l15;
            out[(long)mg * 64 + f] = (o[t0] - mu) * rstd * gam_s[f] + bet_s[f];
          }
      }
  }
}

extern "C" void kernel_launch(void* const* d_in, const int* in_sizes, int n_in,
                              void* d_out, int out_size, void* d_ws, size_t ws_size,
                              hipStream_t stream) {
  const float* node = (const float*)d_in[0];
  const float* edge = (const float*)d_in[1];
  const float* hid = (const float*)d_in[2];
  const int* src = (const int*)d_in[3];
  const int* dst = (const int*)d_in[4];
  const float* W1 = (const float*)d_in[5];
  const float* b1 = (const float*)d_in[6];
  const float* W2 = (const float*)d_in[7];
  const float* b2 = (const float*)d_in[8];
  const float* Wih = (const float*)d_in[9];
  const float* Whh = (const float*)d_in[10];
  const float* bih = (const float*)d_in[11];
  const float* bhh = (const float*)d_in[12];
  const float* gamma = (const float*)d_in[13];
  const float* beta = (const float*)d_in[14];

  char* ws = (char*)d_ws;
  f16* edgeh = (f16*)(ws + O_EDGEH);
  f16* w2g = (f16*)(ws + O_W2G);
  f16* b2g = (f16*)(ws + O_B2G);
  f16* w1g = (f16*)(ws + O_W1G);
  f16* wg = (f16*)(ws + O_WG);
  float* agg = (float*)(ws + O_AGG);
  int* cnt = (int*)(ws + O_CNT);

  hipMemsetAsync(cnt, 0, 8, stream);
  k_fused<<<NB, 256, 0, stream>>>(node, edge, hid, src, dst, W1, b1, W2, b2,
                                  Wih, Whh, bih, bhh, gamma, beta,
                                  edgeh, w1g, w2g, b2g, wg, agg, cnt, (float*)d_out);
}

// Round 9
// 217.151 us; speedup vs baseline: 1.4412x; 1.4412x over previous
//
#include <hip/hip_runtime.h>

#define NEDGE 50000
#define NNODE 12000
#define NB    392
#define NT    100352  // NB*256

typedef _Float16 f16;
typedef _Float16 h8 __attribute__((ext_vector_type(8)));
typedef float f4 __attribute__((ext_vector_type(4)));
typedef float fv16 __attribute__((ext_vector_type(16)));

// workspace layout (bytes) — r5-verified layouts + barrier counter
#define O_EDGEH 0ull            // edge f16 padded [50176][64]        = 6,422,528
#define O_W2G   6422528ull      // swizzled W2 f16 (64 chunks x 16KB) = 1,048,576
#define O_B2G   7471104ull      // swizzled b2 f16 (8KB), follows w2g
#define O_W1G   7479296ull      // swizzled W1 f16 (16KB), absorbs b2 tail overread
#define O_WG    7495680ull      // GRU combined weights f16 (64KB)
#define O_AGG   7561216ull      // agg f32 [12000][64]                = 3,072,000
#define O_CNT   10633216ull     // barrier counter (8B, memset to 0 each launch)

__device__ __forceinline__ fv16 zero16() {
  fv16 z;
#pragma unroll
  for (int i = 0; i < 16; ++i) z[i] = 0.f;
  return z;
}

__global__ __launch_bounds__(256, 2) void k_fused(
    const float* __restrict__ node, const float* __restrict__ edge, const float* __restrict__ hid,
    const int* __restrict__ src, const int* __restrict__ dst,
    const float* __restrict__ W1, const float* __restrict__ b1,
    const float* __restrict__ W2, const float* __restrict__ b2,
    const float* __restrict__ Wih, const float* __restrict__ Whh,
    const float* __restrict__ bih, const float* __restrict__ bhh,
    const float* __restrict__ gamma, const float* __restrict__ beta,
    f16* __restrict__ edgeh, f16* __restrict__ w1g, f16* __restrict__ w2g,
    f16* __restrict__ b2g, f16* __restrict__ wg, float* __restrict__ agg,
    int* __restrict__ cnt, float* __restrict__ out) {
  __shared__ __align__(16) char lds[52736];
  int t = threadIdx.x;
  int bid = blockIdx.x;
  int tid = bid * 256 + t;

  // ================= phase A: prep (grid-strided, r8-verified) =================
  for (int i = tid; i < 192000; i += NT)  // agg zero
    ((f4*)agg)[i] = (f4){0.f, 0.f, 0.f, 0.f};
  for (int i = tid; i < 401408; i += NT) {  // edgeh cast (EPAD rows, pad zeroed)
    long e = (long)i >> 3;
    int c = (i & 7) * 8;
    h8 o = {};
    if (e < NEDGE) {
      const float* p = edge + e * 64 + c;
      f4 v0 = *(const f4*)p, v1 = *(const f4*)(p + 4);
#pragma unroll
      for (int j = 0; j < 4; ++j) { o[j] = (f16)v0[j]; o[4 + j] = (f16)v1[j]; }
    }
    *(h8*)(edgeh + e * 64 + c) = o;
  }
  for (int id = tid; id < 524288; id += NT) {  // w2g swizzle (32x32x16 B-granule order)
    int i = id & 7, l = (id >> 3) & 63, nh = (id >> 9) & 1, s = (id >> 10) & 7, h = id >> 13;
    int n = nh * 32 + (l & 31), j = s * 16 + ((l >> 5) << 3) + i;
    w2g[id] = (f16)W2[(h * 64 + n) * 128 + j];
  }
  for (int id = tid; id < 4096; id += NT) {  // b2g
    int i = id & 7, l = (id >> 3) & 63, nh = (id >> 9) & 1, s = id >> 10;
    int n = nh * 32 + (l & 31), k = s * 16 + ((l >> 5) << 3) + i;
    b2g[id] = (f16)b2[k * 64 + n];
  }
  for (int id = tid; id < 8192; id += NT) {  // w1g
    int i = id & 7, l = (id >> 3) & 63, nt2 = (id >> 9) & 3, s = id >> 11;
    int n = nt2 * 32 + (l & 31), k = s * 16 + ((l >> 5) << 3) + i;
    w1g[id] = (f16)W1[n * 64 + k];
  }
  for (int id = tid; id < 32768; id += NT) {  // wg: GRU combined [128k][256n], 16x16x32 order
    int ii = id & 7, l = (id >> 3) & 63, tt = (id >> 9) & 15, s = id >> 13;
    int k = s * 32 + ((l >> 4) << 3) + ii, n = tt * 16 + (l & 15);
    float v;
    if (n < 128) v = (k < 64) ? Wih[n * 64 + k] : Whh[n * 64 + (k - 64)];
    else if (n < 192) v = (k < 64) ? Wih[n * 64 + k] : 0.f;
    else v = (k < 64) ? 0.f : Whh[(n - 64) * 64 + (k - 64)];
    wg[id] = (f16)v;
  }

  // ---- barrier 1: release once, relaxed spin, acquire once ----
  __syncthreads();
  if (t == 0) {
    __builtin_amdgcn_fence(__ATOMIC_RELEASE, "agent");
    __hip_atomic_fetch_add(cnt, 1, __ATOMIC_RELAXED, __HIP_MEMORY_SCOPE_AGENT);
    while (__hip_atomic_load(cnt, __ATOMIC_RELAXED, __HIP_MEMORY_SCOPE_AGENT) < NB)
      __builtin_amdgcn_s_sleep(16);
    __builtin_amdgcn_fence(__ATOMIC_ACQUIRE, "agent");
  }
  __syncthreads();

  // ================= phase B: msg GEMM + scatter (barrier-free K-loop) =================
  {
    f16* eh_s = (f16*)lds;
    f16* vT = (f16*)(lds + 32768);
    int* ssrc = (int*)(lds + 51200);
    int* sdst = (int*)(lds + 51712);
    float* b1s = (float*)(lds + 52224);
    int e_base = bid * 128;

    if (t < 128) {
      int eg = e_base + t;
      bool valid = eg < NEDGE;
      ssrc[t] = valid ? src[eg] : 0;
      sdst[t] = valid ? dst[eg] : 0;
    } else {
      b1s[t - 128] = b1[t - 128];
    }
    {
      int e = t >> 1, half = t & 1;
      int eg = e_base + e;
      int si = (eg < NEDGE) ? src[eg] : 0;
      const f4* nr = (const f4*)(node + (long)si * 64 + half * 32);
#pragma unroll
      for (int b = 0; b < 4; ++b) {
        f4 v0 = nr[b * 2], v1 = nr[b * 2 + 1];
        h8 pk;
#pragma unroll
        for (int m = 0; m < 4; ++m) { pk[m] = (f16)v0[m]; pk[4 + m] = (f16)v1[m]; }
        *(h8*)(vT + e * 72 + (half * 4 + b) * 8) = pk;
      }
    }
    __syncthreads();

    int wave = t >> 6, lane = t & 63;
    int wm = wave & 1, wn = wave >> 1;
    int l31 = lane & 31, lh = lane >> 5;

    // phase 1: eh = relu(edge @ W1^T + b1) via MFMA (r5-verified)
    {
      h8 afr[2][4];
#pragma unroll
      for (int mt = 0; mt < 2; ++mt)
#pragma unroll
        for (int s = 0; s < 4; ++s)
          afr[mt][s] = *(const h8*)(edgeh + (long)(e_base + wm * 64 + mt * 32 + l31) * 64 + s * 16 + lh * 8);
      h8 bfr[2][4];
#pragma unroll
      for (int nt2 = 0; nt2 < 2; ++nt2)
#pragma unroll
        for (int s = 0; s < 4; ++s)
          bfr[nt2][s] = *(const h8*)(w1g + ((s * 4 + wn * 2 + nt2) * 64 + lane) * 8);
      fv16 acc_eh[2][2];
#pragma unroll
      for (int mt = 0; mt < 2; ++mt)
#pragma unroll
        for (int nt2 = 0; nt2 < 2; ++nt2) acc_eh[mt][nt2] = zero16();
#pragma unroll
      for (int s = 0; s < 4; ++s)
#pragma unroll
        for (int mt = 0; mt < 2; ++mt)
#pragma unroll
          for (int nt2 = 0; nt2 < 2; ++nt2)
            acc_eh[mt][nt2] = __builtin_amdgcn_mfma_f32_32x32x16_f16(afr[mt][s], bfr[nt2][s], acc_eh[mt][nt2], 0, 0, 0);
#pragma unroll
      for (int mt = 0; mt < 2; ++mt)
#pragma unroll
        for (int nt2 = 0; nt2 < 2; ++nt2)
#pragma unroll
          for (int rr = 0; rr < 16; ++rr) {
            int row = (rr & 3) + 8 * (rr >> 2) + 4 * lh;
            int e = wm * 64 + mt * 32 + row;
            int n = wn * 64 + nt2 * 32 + l31;
            float val = fmaxf(acc_eh[mt][nt2][rr] + b1s[n], 0.f);
            int o = n >> 3;
            eh_s[e * 128 + ((o ^ (e & 15)) << 3) + (n & 7)] = (f16)val;
          }
    }
    __syncthreads();

    // phase 2: eh fragments -> registers
    h8 ehreg[2][8];
#pragma unroll
    for (int mt = 0; mt < 2; ++mt) {
      int e = wm * 64 + mt * 32 + l31;
#pragma unroll
      for (int s = 0; s < 8; ++s) {
        int o = (s * 2 + lh) ^ (e & 15);
        ehreg[mt][s] = *(const h8*)(eh_s + e * 128 + o * 8);
      }
    }

    // phase 3: K-loop, B global->register double-buffered, NO barriers
    fv16 acc[2];
    acc[0] = zero16(); acc[1] = zero16();
    const f16* vr0 = vT + (wm * 64 + l31) * 72;
    const f16* vr1 = vr0 + 32 * 72;
    const f16* bbase = w2g + wn * 512 + lane * 8;     // + h*8192 + s*1024
    const f16* b2base = b2g + wn * 512 + lane * 8;    // K=64 tail (s>=4 overreads w1g: unused)

    h8 B0[8], B1[8];
#pragma unroll
    for (int s = 0; s < 8; ++s) B0[s] = *(const h8*)(bbase + s * 1024);

#pragma unroll 1
    for (int hb = 0; hb < 8; ++hb) {
      h8 vh0 = *(const h8*)(vr0 + hb * 8);
      h8 vh1 = *(const h8*)(vr1 + hb * 8);
#pragma unroll
      for (int q = 0; q < 4; ++q) {
        int h = hb * 8 + q * 2;
        {  // prefetch h+1 -> B1 ; compute h with B0
          const f16* np = bbase + (long)(h + 1) * 8192;
#pragma unroll
          for (int s = 0; s < 8; ++s) B1[s] = *(const h8*)(np + s * 1024);
          f16 v0 = vh0[q * 2], v1 = vh1[q * 2];
#pragma unroll
          for (int s = 0; s < 8; ++s) {
            h8 a0 = ehreg[0][s] * v0;
            acc[0] = __builtin_amdgcn_mfma_f32_32x32x16_f16(a0, B0[s], acc[0], 0, 0, 0);
            h8 a1 = ehreg[1][s] * v1;
            acc[1] = __builtin_amdgcn_mfma_f32_32x32x16_f16(a1, B0[s], acc[1], 0, 0, 0);
          }
        }
        {  // prefetch h+2 -> B0 (h+2==64 -> b2 tail) ; compute h+1 with B1
          const f16* np = (h + 2 < 64) ? (bbase + (long)(h + 2) * 8192) : b2base;
#pragma unroll
          for (int s = 0; s < 8; ++s) B0[s] = *(const h8*)(np + s * 1024);
          f16 v0 = vh0[q * 2 + 1], v1 = vh1[q * 2 + 1];
#pragma unroll
          for (int s = 0; s < 8; ++s) {
            h8 a0 = ehreg[0][s] * v0;
            acc[0] = __builtin_amdgcn_mfma_f32_32x32x16_f16(a0, B1[s], acc[0], 0, 0, 0);
            h8 a1 = ehreg[1][s] * v1;
            acc[1] = __builtin_amdgcn_mfma_f32_32x32x16_f16(a1, B1[s], acc[1], 0, 0, 0);
          }
        }
      }
    }
    // b2 bias tail (K=64): A = v directly, B0[0..3]
#pragma unroll
    for (int s = 0; s < 4; ++s) {
      h8 a0 = *(const h8*)(vr0 + (s * 2 + lh) * 8);
      h8 a1 = *(const h8*)(vr1 + (s * 2 + lh) * 8);
      acc[0] = __builtin_amdgcn_mfma_f32_32x32x16_f16(a0, B0[s], acc[0], 0, 0, 0);
      acc[1] = __builtin_amdgcn_mfma_f32_32x32x16_f16(a1, B0[s], acc[1], 0, 0, 0);
    }
    // epilogue: atomic scatter
    int n = wn * 32 + l31;
#pragma unroll
    for (int mt = 0; mt < 2; ++mt)
#pragma unroll
      for (int r = 0; r < 16; ++r) {
        int el = wm * 64 + mt * 32 + (r & 3) + 8 * (r >> 2) + 4 * lh;
        if (e_base + el < NEDGE)
          atomicAdd(&agg[(long)sdst[el] * 64 + n], acc[mt][r]);
      }
  }

  // ---- barrier 2: atomics-only phase -> no release needed; non-C blocks arrive & exit ----
  __syncthreads();
  if (bid >= 94) {
    if (t == 0) __hip_atomic_fetch_add(cnt, 1, __ATOMIC_RELAXED, __HIP_MEMORY_SCOPE_AGENT);
    return;
  }
  if (t == 0) {
    __hip_atomic_fetch_add(cnt, 1, __ATOMIC_RELAXED, __HIP_MEMORY_SCOPE_AGENT);
    while (__hip_atomic_load(cnt, __ATOMIC_RELAXED, __HIP_MEMORY_SCOPE_AGENT) < 2 * NB)
      __builtin_amdgcn_s_sleep(16);
    __builtin_amdgcn_fence(__ATOMIC_ACQUIRE, "agent");
  }
  __syncthreads();

  // ================= phase C: GRU + LayerNorm (blocks 0..93, r5-verified) =================
  {
    f16* xh_s = (f16*)lds;
    float* bsum = (float*)(lds + 34816);
    float* bin_s = (float*)(lds + 35328);
    float* bhn_s = (float*)(lds + 35584);
    float* gam_s = (float*)(lds + 35840);
    float* bet_s = (float*)(lds + 36096);
    int n0 = bid * 128;

    if (t < 128) bsum[t] = bih[t] + bhh[t];
    else if (t < 192) bin_s[t - 128] = bih[t];
    else bhn_s[t - 192] = bhh[t - 64];
    if (t < 64) gam_s[t] = gamma[t];
    else if (t < 128) bet_s[t - 64] = beta[t - 64];

    {
      int m = t >> 1, half = t & 1;
      int mg = n0 + m;
      bool vld = mg < NNODE;
      const float* sp = half ? (hid + (long)mg * 64) : (agg + (long)mg * 64);
#pragma unroll
      for (int jj = 0; jj < 8; ++jj) {
        f4 v0 = {0, 0, 0, 0}, v1 = {0, 0, 0, 0};
        if (vld) { v0 = *(const f4*)(sp + jj * 8); v1 = *(const f4*)(sp + jj * 8 + 4); }
        h8 pk;
#pragma unroll
        for (int m2 = 0; m2 < 4; ++m2) {
          pk[m2] = (f16)(half ? v0[m2] : fmaxf(v0[m2], 0.f));
          pk[4 + m2] = (f16)(half ? v1[m2] : fmaxf(v1[m2], 0.f));
        }
        *(h8*)(xh_s + m * 136 + half * 64 + jj * 8) = pk;
      }
    }
    __syncthreads();

    int wave = t >> 6, lane = t & 63;
    int l15 = lane & 15, lq = lane >> 4;

    f4 acc[2][16];
#pragma unroll
    for (int g = 0; g < 2; ++g)
#pragma unroll
      for (int tt = 0; tt < 16; ++tt) acc[g][tt] = (f4){0.f, 0.f, 0.f, 0.f};
#pragma unroll
    for (int s = 0; s < 4; ++s) {
      h8 a0 = *(const h8*)(xh_s + (wave * 32 + l15) * 136 + s * 32 + lq * 8);
      h8 a1 = *(const h8*)(xh_s + (wave * 32 + 16 + l15) * 136 + s * 32 + lq * 8);
#pragma unroll
      for (int tt = 0; tt < 16; ++tt) {
        h8 b = *(const h8*)(wg + ((s * 16 + tt) * 64 + lane) * 8);
        acc[0][tt] = __builtin_amdgcn_mfma_f32_16x16x32_f16(a0, b, acc[0][tt], 0, 0, 0);
        acc[1][tt] = __builtin_amdgcn_mfma_f32_16x16x32_f16(a1, b, acc[1][tt], 0, 0, 0);
      }
    }
#pragma unroll
    for (int g = 0; g < 2; ++g)
#pragma unroll
      for (int r = 0; r < 4; ++r) {
        int mg = n0 + wave * 32 + g * 16 + lq * 4 + r;
        bool vld = mg < NNODE;
        float o[4], ssum = 0.f, s2 = 0.f;
#pragma unroll
        for (int t0 = 0; t0 < 4; ++t0) {
          int f = t0 * 16 + l15;
          float rpre = acc[g][t0][r] + bsum[f];
          float zpre = acc[g][4 + t0][r] + bsum[64 + f];
          float ginv = acc[g][8 + t0][r] + bin_s[f];
          float ghnv = acc[g][12 + t0][r] + bhn_s[f];
          float rr = 1.f / (1.f + __expf(-rpre));
          float zz = 1.f / (1.f + __expf(-zpre));
          float hv = vld ? hid[(long)mg * 64 + f] : 0.f;
          float nn = tanhf(ginv + rr * ghnv);
          float oo = (1.f - zz) * nn + zz * hv;
          o[t0] = oo; ssum += oo; s2 += oo * oo;
        }
#pragma unroll
        for (int d = 1; d < 16; d <<= 1) {
          ssum += __shfl_xor(ssum, d);
          s2 += __shfl_xor(s2, d);
        }
        float mu = ssum * (1.f / 64.f);
        float var = s2 * (1.f / 64.f) - mu * mu;
        float rstd = rsqrtf(var + 1e-5f);
        if (vld)
#pragma unroll
          for (int t0 = 0; t0 < 4; ++t0) {
            int f = t0 * 16 + l15;
            out[(long)mg * 64 + f] = (o[t0] - mu) * rstd * gam_s[f] + bet_s[f];
          }
      }
  }
}

extern "C" void kernel_launch(void* const* d_in, const int* in_sizes, int n_in,
                              void* d_out, int out_size, void* d_ws, size_t ws_size,
                              hipStream_t stream) {
  const float* node = (const float*)d_in[0];
  const float* edge = (const float*)d_in[1];
  const float* hid = (const float*)d_in[2];
  const int* src = (const int*)d_in[3];
  const int* dst = (const int*)d_in[4];
  const float* W1 = (const float*)d_in[5];
  const float* b1 = (const float*)d_in[6];
  const float* W2 = (const float*)d_in[7];
  const float* b2 = (const float*)d_in[8];
  const float* Wih = (const float*)d_in[9];
  const float* Whh = (const float*)d_in[10];
  const float* bih = (const float*)d_in[11];
  const float* bhh = (const float*)d_in[12];
  const float* gamma = (const float*)d_in[13];
  const float* beta = (const float*)d_in[14];

  char* ws = (char*)d_ws;
  f16* edgeh = (f16*)(ws + O_EDGEH);
  f16* w2g = (f16*)(ws + O_W2G);
  f16* b2g = (f16*)(ws + O_B2G);
  f16* w1g = (f16*)(ws + O_W1G);
  f16* wg = (f16*)(ws + O_WG);
  float* agg = (float*)(ws + O_AGG);
  int* cnt = (int*)(ws + O_CNT);

  hipMemsetAsync(cnt, 0, 8, stream);
  k_fused<<<NB, 256, 0, stream>>>(node, edge, hid, src, dst, W1, b1, W2, b2,
                                  Wih, Whh, bih, bhh, gamma, beta,
                                  edgeh, w1g, w2g, b2g, wg, agg, cnt, (float*)d_out);
}